// Round 1
// baseline (5463.091 us; speedup 1.0000x reference)
//
#include <hip/hip_runtime.h>

#define EPSV 1e-5f

__device__ __forceinline__ float wredsum(float v){
  #pragma unroll
  for (int o = 32; o > 0; o >>= 1) v += __shfl_xor(v, o, 64);
  return v;
}
__device__ __forceinline__ float wredmax(float v){
  #pragma unroll
  for (int o = 32; o > 0; o >>= 1) v = fmaxf(v, __shfl_xor(v, o, 64));
  return v;
}
__device__ __forceinline__ float wredmin(float v){
  #pragma unroll
  for (int o = 32; o > 0; o >>= 1) v = fminf(v, __shfl_xor(v, o, 64));
  return v;
}
__device__ __forceinline__ float fsig(float x){ return 1.0f / (1.0f + __expf(-x)); }
__device__ __forceinline__ float ftanh(float x){ return 1.0f - 2.0f / (__expf(2.0f * x) + 1.0f); }

// ---------------- Stage 1: points -> lin1(6->8)+relu -> fuse(C=8) -> u1 [N,16] + stats
__global__ __launch_bounds__(256) void k_stage1(
    const float* __restrict__ pts, const float* __restrict__ f2d,
    const float* __restrict__ Wc, const float* __restrict__ bc,
    const float* __restrict__ W2d, const float* __restrict__ b2d,
    const float* __restrict__ W3d, const float* __restrict__ b3d,
    const float* __restrict__ Watt, const float* __restrict__ batt,
    float* __restrict__ uout, float* __restrict__ gS, float* __restrict__ gQ, int N)
{
  const int tid = threadIdx.x;
  const int n = blockIdx.x * 256 + tid;
  const bool act = n < N;
  const size_t nc = act ? (size_t)n : 0;
  __shared__ float sS[16], sQ[16];
  if (tid < 16){ sS[tid] = 0.f; sQ[tid] = 0.f; }
  __syncthreads();

  const float* p = pts + nc * 10;
  float xin[6];
  xin[0]=p[0]; xin[1]=p[1]; xin[2]=p[2]; xin[3]=p[7]; xin[4]=p[8]; xin[5]=p[9];
  float x1[8];
  #pragma unroll
  for (int i = 0; i < 8; i++){
    float a = bc[i];
    #pragma unroll
    for (int j = 0; j < 6; j++) a = fmaf(Wc[i*6+j], xin[j], a);
    x1[i] = fmaxf(a, 0.f);
  }
  float f[8];
  const float* fp = f2d + nc * 8;
  #pragma unroll
  for (int j = 0; j < 8; j++) f[j] = fp[j];
  float d2d[8];
  #pragma unroll
  for (int i = 0; i < 8; i++){
    float a = b2d[i];
    #pragma unroll
    for (int j = 0; j < 8; j++) a = fmaf(W2d[i*8+j], f[j], a);
    d2d[i] = a;
  }
  float mid[8];
  #pragma unroll
  for (int i = 0; i < 8; i++){
    float a = b3d[i] + d2d[i];
    #pragma unroll
    for (int j = 0; j < 8; j++) a = fmaf(W3d[i*8+j], x1[j], a);
    mid[i] = ftanh(a);
  }
  float r[8];
  #pragma unroll
  for (int i = 0; i < 8; i++){
    float a = batt[i];
    #pragma unroll
    for (int j = 0; j < 8; j++) a = fmaf(Watt[i*8+j], mid[j], a);
    r[i] = fsig(a) * d2d[i];
  }
  float* urow = uout + nc * 16;
  if (act){
    *(float4*)(urow + 0)  = make_float4(x1[0], x1[1], x1[2], x1[3]);
    *(float4*)(urow + 4)  = make_float4(x1[4], x1[5], x1[6], x1[7]);
    *(float4*)(urow + 8)  = make_float4(r[0], r[1], r[2], r[3]);
    *(float4*)(urow + 12) = make_float4(r[4], r[5], r[6], r[7]);
  }
  #pragma unroll
  for (int i = 0; i < 8; i++){
    float v = act ? x1[i] : 0.f;
    float s = wredsum(v), q = wredsum(v * v);
    if ((tid & 63) == 0){ atomicAdd(&sS[i], s); atomicAdd(&sQ[i], q); }
    float v2 = act ? r[i] : 0.f;
    float s2 = wredsum(v2), q2 = wredsum(v2 * v2);
    if ((tid & 63) == 0){ atomicAdd(&sS[8+i], s2); atomicAdd(&sQ[8+i], q2); }
  }
  __syncthreads();
  if (tid < 16){ atomicAdd(&gS[tid], sS[tid]); atomicAdd(&gQ[tid], sQ[tid]); }
}

// ---------------- Generic mid stage: BN(prev stats) -> lin(C->C)+relu -> fuse(C) -> u [N,2C] + stats
// PF: also write BN output (point_feature) to output rows [256..256+C)
template<int C, bool PF>
__global__ __launch_bounds__(256) void k_stage(
    const float* __restrict__ uprev, const float* __restrict__ pS, const float* __restrict__ pQ,
    const float* __restrict__ gam, const float* __restrict__ bet,
    const float* __restrict__ Wc, const float* __restrict__ bc,
    const float* __restrict__ f2d,
    const float* __restrict__ W2d, const float* __restrict__ b2d,
    const float* __restrict__ W3d, const float* __restrict__ b3d,
    const float* __restrict__ Watt, const float* __restrict__ batt,
    float* __restrict__ uout, float* __restrict__ gS, float* __restrict__ gQ,
    float* __restrict__ pfout, float invN, int N)
{
  const int tid = threadIdx.x;
  const int n = blockIdx.x * 256 + tid;
  const bool act = n < N;
  const size_t nc = act ? (size_t)n : 0;
  __shared__ float sA[C], sB[C], sS[2*C], sQ[2*C];
  if (tid < C){
    float m = pS[tid] * invN;
    float v = pQ[tid] * invN - m * m;
    float a = gam[tid] * rsqrtf(v + EPSV);
    sA[tid] = a; sB[tid] = fmaf(-a, m, bet[tid]);
  }
  if (tid < 2*C){ sS[tid] = 0.f; sQ[tid] = 0.f; }
  __syncthreads();

  float y[C];
  { const float* up = uprev + nc * C;
    #pragma unroll
    for (int j = 0; j < C; j++) y[j] = fmaf(sA[j], up[j], sB[j]); }
  if (PF){
    #pragma unroll
    for (int i = 0; i < C; i++) if (act) pfout[(size_t)i * N + n] = y[i];
  }
  float x[C];
  #pragma unroll
  for (int i = 0; i < C; i++){
    float a0 = bc[i], a1 = 0.f, a2 = 0.f, a3 = 0.f;
    const float* w = Wc + i * C;
    #pragma unroll
    for (int j = 0; j < C; j += 4){
      a0 = fmaf(w[j+0], y[j+0], a0); a1 = fmaf(w[j+1], y[j+1], a1);
      a2 = fmaf(w[j+2], y[j+2], a2); a3 = fmaf(w[j+3], y[j+3], a3);
    }
    x[i] = fmaxf((a0 + a1) + (a2 + a3), 0.f);
  }
  float* urow = uout + nc * (2 * C);
  if (act){
    #pragma unroll
    for (int i = 0; i < C; i += 4)
      *(float4*)(urow + i) = make_float4(x[i], x[i+1], x[i+2], x[i+3]);
  }
  #pragma unroll
  for (int i = 0; i < C; i++){
    float v = act ? x[i] : 0.f;
    float s = wredsum(v), q = wredsum(v * v);
    if ((tid & 63) == 0){ atomicAdd(&sS[i], s); atomicAdd(&sQ[i], q); }
  }
  float f[C];
  { const float* fp2 = f2d + nc * C;
    #pragma unroll
    for (int j = 0; j < C; j++) f[j] = fp2[j]; }
  float d2d[C];
  #pragma unroll
  for (int i = 0; i < C; i++){
    float a0 = b2d[i], a1 = 0.f, a2 = 0.f, a3 = 0.f;
    const float* w = W2d + i * C;
    #pragma unroll
    for (int j = 0; j < C; j += 4){
      a0 = fmaf(w[j+0], f[j+0], a0); a1 = fmaf(w[j+1], f[j+1], a1);
      a2 = fmaf(w[j+2], f[j+2], a2); a3 = fmaf(w[j+3], f[j+3], a3);
    }
    d2d[i] = (a0 + a1) + (a2 + a3);
  }
  float mid[C];
  #pragma unroll
  for (int i = 0; i < C; i++){
    float a0 = b3d[i] + d2d[i], a1 = 0.f, a2 = 0.f, a3 = 0.f;
    const float* w = W3d + i * C;
    #pragma unroll
    for (int j = 0; j < C; j += 4){
      a0 = fmaf(w[j+0], x[j+0], a0); a1 = fmaf(w[j+1], x[j+1], a1);
      a2 = fmaf(w[j+2], x[j+2], a2); a3 = fmaf(w[j+3], x[j+3], a3);
    }
    mid[i] = ftanh((a0 + a1) + (a2 + a3));
  }
  // att * d2d, reusing x[] (dead) as the result buffer
  #pragma unroll
  for (int i = 0; i < C; i++){
    float a0 = batt[i], a1 = 0.f, a2 = 0.f, a3 = 0.f;
    const float* w = Watt + i * C;
    #pragma unroll
    for (int j = 0; j < C; j += 4){
      a0 = fmaf(w[j+0], mid[j+0], a0); a1 = fmaf(w[j+1], mid[j+1], a1);
      a2 = fmaf(w[j+2], mid[j+2], a2); a3 = fmaf(w[j+3], mid[j+3], a3);
    }
    x[i] = fsig((a0 + a1) + (a2 + a3)) * d2d[i];
  }
  if (act){
    #pragma unroll
    for (int i = 0; i < C; i += 4)
      *(float4*)(urow + C + i) = make_float4(x[i], x[i+1], x[i+2], x[i+3]);
  }
  #pragma unroll
  for (int i = 0; i < C; i++){
    float v = act ? x[i] : 0.f;
    float s = wredsum(v), q = wredsum(v * v);
    if ((tid & 63) == 0){ atomicAdd(&sS[C+i], s); atomicAdd(&sQ[C+i], q); }
  }
  __syncthreads();
  if (tid < 2*C){ atomicAdd(&gS[tid], sS[tid]); atomicAdd(&gQ[tid], sQ[tid]); }
}

// ---------------- Stage 5: BN4 -> lin5(128->256)+relu -> per-channel sum/sumsq/max/min (no z materialization)
__global__ __launch_bounds__(256) void k_stage5(
    const float* __restrict__ u4, const float* __restrict__ pS, const float* __restrict__ pQ,
    const float* __restrict__ gam, const float* __restrict__ bet,
    const float* __restrict__ W5, const float* __restrict__ b5,
    float* __restrict__ gS, float* __restrict__ gQ,
    int* __restrict__ gMx, int* __restrict__ gMn,
    float invN, int N)
{
  const int tid = threadIdx.x;
  const int n = blockIdx.x * 256 + tid;
  const bool act = n < N;
  const size_t nc = act ? (size_t)n : 0;
  __shared__ float sA[128], sB[128];
  __shared__ float sS[256], sQ[256];
  __shared__ int sMx[256], sMn[256];
  if (tid < 128){
    float m = pS[tid] * invN;
    float v = pQ[tid] * invN - m * m;
    float a = gam[tid] * rsqrtf(v + EPSV);
    sA[tid] = a; sB[tid] = fmaf(-a, m, bet[tid]);
  }
  sS[tid] = 0.f; sQ[tid] = 0.f; sMx[tid] = 0; sMn[tid] = 0x7f800000;
  __syncthreads();

  float y[128];
  const float* up = u4 + nc * 128;
  #pragma unroll
  for (int j = 0; j < 128; j++) y[j] = fmaf(sA[j], up[j], sB[j]);

  for (int i = 0; i < 256; i++){   // rolled outer loop; weights stream via scalar cache
    const float* w = W5 + (size_t)i * 128;
    float a0 = 0.f, a1 = 0.f, a2 = 0.f, a3 = 0.f;
    #pragma unroll
    for (int j = 0; j < 128; j += 4){
      a0 = fmaf(w[j+0], y[j+0], a0); a1 = fmaf(w[j+1], y[j+1], a1);
      a2 = fmaf(w[j+2], y[j+2], a2); a3 = fmaf(w[j+3], y[j+3], a3);
    }
    float z = fmaxf((a0 + a1) + (a2 + a3) + b5[i], 0.f);
    float zs = act ? z : 0.f;
    float s = wredsum(zs);
    float q = wredsum(zs * zs);
    float mx = wredmax(zs);  // z>=0, inactive contribute 0 (neutral: real max >= 0)
    float mn = wredmin(act ? z : __int_as_float(0x7f800000));
    if ((tid & 63) == 0){
      atomicAdd(&sS[i], s); atomicAdd(&sQ[i], q);
      atomicMax(&sMx[i], __float_as_int(mx));
      atomicMin(&sMn[i], __float_as_int(mn));
    }
  }
  __syncthreads();
  atomicAdd(&gS[tid], sS[tid]);
  atomicAdd(&gQ[tid], sQ[tid]);
  atomicMax(&gMx[tid], sMx[tid]);
  atomicMin(&gMn[tid], sMn[tid]);
}

// ---------------- Fill glob rows: out[c*N + n] = BN5(max-pool), c in [0,256)
__global__ __launch_bounds__(256) void k_fill(
    const float* __restrict__ gS, const float* __restrict__ gQ,
    const int* __restrict__ gMx, const int* __restrict__ gMn,
    const float* __restrict__ g5, const float* __restrict__ be5,
    float* __restrict__ out, float invN, int N)
{
  const int c = blockIdx.y;
  float m = gS[c] * invN;
  float v = gQ[c] * invN - m * m;
  float a = g5[c] * rsqrtf(v + EPSV);
  float d = fmaf(-a, m, be5[c]);
  float zx = __int_as_float(gMx[c]);
  float zn = __int_as_float(gMn[c]);
  float glob = (a >= 0.f) ? fmaf(a, zx, d) : fmaf(a, zn, d);
  int n0 = (blockIdx.x * 256 + threadIdx.x) * 4;
  if (n0 < N)  // N % 4 == 0
    *(float4*)(out + (size_t)c * N + n0) = make_float4(glob, glob, glob, glob);
}

extern "C" void kernel_launch(void* const* d_in, const int* in_sizes, int n_in,
                              void* d_out, int out_size, void* d_ws, size_t ws_size,
                              hipStream_t stream) {
  const int N = in_sizes[0] / 10;
  auto F = [&](int i){ return (const float*)d_in[i]; };
  const float* P  = F(0);
  const float* F1 = F(1); const float* F2 = F(2); const float* F3 = F(3); const float* F4 = F(4);
  const float* Wc1 = F(5);  const float* Bc1 = F(6);
  const float* Wc2 = F(7);  const float* Bc2 = F(8);
  const float* Wc3 = F(9);  const float* Bc3 = F(10);
  const float* Wc4 = F(11); const float* Bc4 = F(12);
  const float* Wc5 = F(13); const float* Bc5 = F(14);
  const float* G1 = F(15); const float* BE1 = F(16);
  const float* G2 = F(17); const float* BE2 = F(18);
  const float* G3 = F(19); const float* BE3 = F(20);
  const float* G4 = F(21); const float* BE4 = F(22);
  const float* G5 = F(23); const float* BE5 = F(24);
  // fusers: base 25 + (stage-1)*6 : w2d, b2d, w3d, b3d, watt, batt
  const float *W2d1=F(25), *B2d1=F(26), *W3d1=F(27), *B3d1=F(28), *Wat1=F(29), *Bat1=F(30);
  const float *W2d2=F(31), *B2d2=F(32), *W3d2=F(33), *B3d2=F(34), *Wat2=F(35), *Bat2=F(36);
  const float *W2d3=F(37), *B2d3=F(38), *W3d3=F(39), *B3d3=F(40), *Wat3=F(41), *Bat3=F(42);
  const float *W2d4=F(43), *B2d4=F(44), *W3d4=F(45), *B3d4=F(46), *Wat4=F(47), *Bat4=F(48);

  float* out = (float*)d_out;
  // Scratch aliased into the glob region of the output (rows 0..255 = 256*N floats,
  // written last by k_fill). u1..u4 need 240*N floats <= 256*N.
  float* u1 = out;                       // [N,16]
  float* u2 = u1 + (size_t)N * 16;       // [N,32]
  float* u3 = u2 + (size_t)N * 32;       // [N,64]
  float* u4 = u3 + (size_t)N * 64;       // [N,128], ends at 240*N
  float* pf = out + (size_t)256 * N;     // rows 256..319: point_feature^T

  // Stats in d_ws (6016 bytes): S1 Q1 S2 Q2 S3 Q3 S4 Q4 S5 Q5 MX MN
  float* st = (float*)d_ws;
  float* S1 = st;        float* Q1 = st + 16;
  float* S2 = st + 32;   float* Q2 = st + 64;
  float* S3 = st + 96;   float* Q3 = st + 160;
  float* S4 = st + 224;  float* Q4 = st + 352;
  float* S5 = st + 480;  float* Q5 = st + 736;
  int*   MX = (int*)(st + 992);
  int*   MN = (int*)(st + 1248);
  hipMemsetAsync(st, 0, 1248 * sizeof(float), stream);          // sums + sumsq + MX (0)
  hipMemsetAsync(MN, 0x7f, 256 * sizeof(float), stream);        // MN = 0x7f7f7f7f (large +float)

  const int nb = (N + 255) / 256;
  const float invN = 1.0f / (float)N;

  k_stage1<<<nb, 256, 0, stream>>>(P, F1, Wc1, Bc1, W2d1, B2d1, W3d1, B3d1, Wat1, Bat1,
                                   u1, S1, Q1, N);
  k_stage<16, false><<<nb, 256, 0, stream>>>(u1, S1, Q1, G1, BE1, Wc2, Bc2, F2,
                                             W2d2, B2d2, W3d2, B3d2, Wat2, Bat2,
                                             u2, S2, Q2, nullptr, invN, N);
  k_stage<32, false><<<nb, 256, 0, stream>>>(u2, S2, Q2, G2, BE2, Wc3, Bc3, F3,
                                             W2d3, B2d3, W3d3, B3d3, Wat3, Bat3,
                                             u3, S3, Q3, nullptr, invN, N);
  k_stage<64, true><<<nb, 256, 0, stream>>>(u3, S3, Q3, G3, BE3, Wc4, Bc4, F4,
                                            W2d4, B2d4, W3d4, B3d4, Wat4, Bat4,
                                            u4, S4, Q4, pf, invN, N);
  k_stage5<<<nb, 256, 0, stream>>>(u4, S4, Q4, G4, BE4, Wc5, Bc5,
                                   S5, Q5, MX, MN, invN, N);
  dim3 gfill((N / 4 + 255) / 256, 256, 1);
  k_fill<<<gfill, 256, 0, stream>>>(S5, Q5, MX, MN, G5, BE5, out, invN, N);
}